// Round 2
// baseline (952.754 us; speedup 1.0000x reference)
//
#include <hip/hip_runtime.h>
#include <hip/hip_bf16.h>
#include <math.h>

#define N_NODES 50000
#define IN_DIM  1000
#define HIDDEN  256
#define OUT_DIM 2
#define N_EDGES 1600000

// NOTE: harness passes integer inputs as int32 (edge_index: [2, N_EDGES] int32).

// ---------------- degree histogram ----------------
__global__ void hist_kernel(const int* __restrict__ ei, int* __restrict__ cnt) {
    int e = blockIdx.x * blockDim.x + threadIdx.x;
    int stride = gridDim.x * blockDim.x;
    for (; e < N_EDGES; e += stride) {
        int d = ei[N_EDGES + e];   // dst row
        if ((unsigned)d < N_NODES) atomicAdd(&cnt[d], 1);
    }
}

// ---------------- exclusive scan (single block) + dinv ----------------
__global__ void scan_kernel(const int* __restrict__ cnt, int* __restrict__ rowoff,
                            int* __restrict__ cursor, float* __restrict__ dinv) {
    __shared__ int sdata[1024];
    __shared__ int scarry;
    int tid = threadIdx.x;
    if (tid == 0) scarry = 0;
    __syncthreads();
    for (int base = 0; base < N_NODES; base += 1024) {
        int i = base + tid;
        int v = (i < N_NODES) ? cnt[i] : 0;
        sdata[tid] = v;
        __syncthreads();
        for (int off = 1; off < 1024; off <<= 1) {
            int t = (tid >= off) ? sdata[tid - off] : 0;
            __syncthreads();
            sdata[tid] += t;
            __syncthreads();
        }
        int incl = sdata[tid];
        int carry = scarry;
        if (i < N_NODES) {
            int ro = carry + incl - v;       // exclusive
            rowoff[i] = ro;
            cursor[i] = ro;
            dinv[i]  = rsqrtf((float)v + 1.0f);  // +1 self-loop
        }
        __syncthreads();
        if (tid == 1023) scarry = carry + incl;
        __syncthreads();
    }
    if (tid == 0) rowoff[N_NODES] = scarry;
}

// ---------------- counting-sort scatter: CSR src lists ----------------
__global__ void scatter_kernel(const int* __restrict__ ei,
                               int* __restrict__ cursor, int* __restrict__ csr) {
    int e = blockIdx.x * blockDim.x + threadIdx.x;
    int stride = gridDim.x * blockDim.x;
    for (; e < N_EDGES; e += stride) {
        int s = ei[e];
        int d = ei[N_EDGES + e];
        if ((unsigned)d < N_NODES && (unsigned)s < N_NODES) {
            int pos = atomicAdd(&cursor[d], 1);
            csr[pos] = s;
        }
    }
}

// ---------------- GEMM1: g1 = dinv[row] * (X @ W1)  [50000,1000]x[1000,256]
// 128x128 tile, BK=16, 256 threads, 8x8 microtile, fp32 vector FMA
__global__ __launch_bounds__(256) void gemm1_kernel(const float* __restrict__ X,
                                                    const float* __restrict__ W,
                                                    const float* __restrict__ dinv,
                                                    float* __restrict__ G) {
    __shared__ float As[16][132];   // [k][row], +4 pad keeps 16B alignment
    __shared__ float Bs[16][132];   // [k][col]
    const int tid = threadIdx.x;
    const int tx = tid & 15, ty = tid >> 4;
    const int m0 = blockIdx.x * 128;
    const int n0 = blockIdx.y * 128;

    float acc[8][8] = {};

    for (int k0 = 0; k0 < IN_DIM; k0 += 16) {
        // load A tile: 128 rows x 16 k = 512 float4s, 2 per thread
        #pragma unroll
        for (int q = 0; q < 2; ++q) {
            int f = tid * 2 + q;
            int row = f >> 2;
            int kq = f & 3;
            int gr = m0 + row;
            int gk = k0 + kq * 4;
            float4 v = make_float4(0.f, 0.f, 0.f, 0.f);
            if (gr < N_NODES && gk < IN_DIM)   // gk%4==0; gk<1000 => gk+3<=999 ok
                v = *(const float4*)&X[(size_t)gr * IN_DIM + gk];
            As[kq * 4 + 0][row] = v.x;
            As[kq * 4 + 1][row] = v.y;
            As[kq * 4 + 2][row] = v.z;
            As[kq * 4 + 3][row] = v.w;
        }
        // load B tile: 16 k x 128 cols
        #pragma unroll
        for (int q = 0; q < 2; ++q) {
            int f = tid * 2 + q;
            int kk = f >> 5;
            int nq = f & 31;
            int gk = k0 + kk;
            float4 v = make_float4(0.f, 0.f, 0.f, 0.f);
            if (gk < IN_DIM)
                v = *(const float4*)&W[(size_t)gk * HIDDEN + n0 + nq * 4];
            *(float4*)&Bs[kk][nq * 4] = v;
        }
        __syncthreads();

        #pragma unroll
        for (int kk = 0; kk < 16; ++kk) {
            float a[8], b[8];
            *(float4*)&a[0] = *(const float4*)&As[kk][ty * 8];
            *(float4*)&a[4] = *(const float4*)&As[kk][ty * 8 + 4];
            *(float4*)&b[0] = *(const float4*)&Bs[kk][tx * 8];
            *(float4*)&b[4] = *(const float4*)&Bs[kk][tx * 8 + 4];
            #pragma unroll
            for (int i = 0; i < 8; ++i)
                #pragma unroll
                for (int j = 0; j < 8; ++j)
                    acc[i][j] += a[i] * b[j];
        }
        __syncthreads();
    }

    #pragma unroll
    for (int i = 0; i < 8; ++i) {
        int gr = m0 + ty * 8 + i;
        if (gr >= N_NODES) continue;
        float dv = dinv[gr];
        float4 o0, o1;
        o0.x = dv * acc[i][0]; o0.y = dv * acc[i][1]; o0.z = dv * acc[i][2]; o0.w = dv * acc[i][3];
        o1.x = dv * acc[i][4]; o1.y = dv * acc[i][5]; o1.z = dv * acc[i][6]; o1.w = dv * acc[i][7];
        float* dst = &G[(size_t)gr * HIDDEN + n0 + tx * 8];
        *(float4*)dst = o0;
        *(float4*)(dst + 4) = o1;
    }
}

// ---------------- agg1: z = relu(dinv[d]*(g1[d] + sum g1[src]) + b1)
// one wave per node, lane owns 4 consecutive cols (float4)
__global__ __launch_bounds__(256) void agg1_kernel(const float* __restrict__ G,
                                                   const int* __restrict__ csr,
                                                   const int* __restrict__ rowoff,
                                                   const int* __restrict__ cnt,
                                                   const float* __restrict__ dinv,
                                                   const float* __restrict__ b1,
                                                   float* __restrict__ Z) {
    int wave = threadIdx.x >> 6;
    int lane = threadIdx.x & 63;
    int d = blockIdx.x * 4 + wave;
    if (d >= N_NODES) return;
    int c0 = lane * 4;
    float4 acc = *(const float4*)&G[(size_t)d * HIDDEN + c0];   // self loop
    int beg = rowoff[d], num = cnt[d];
    for (int e = 0; e < num; ++e) {
        int s = csr[beg + e];
        float4 v = *(const float4*)&G[(size_t)s * HIDDEN + c0];
        acc.x += v.x; acc.y += v.y; acc.z += v.z; acc.w += v.w;
    }
    float dv = dinv[d];
    float4 bb = *(const float4*)&b1[c0];
    float4 o;
    o.x = fmaxf(dv * acc.x + bb.x, 0.f);
    o.y = fmaxf(dv * acc.y + bb.y, 0.f);
    o.z = fmaxf(dv * acc.z + bb.z, 0.f);
    o.w = fmaxf(dv * acc.w + bb.w, 0.f);
    *(float4*)&Z[(size_t)d * HIDDEN + c0] = o;
}

// ---------------- gemm2 + scale: g2[i] = dinv[i] * (z[i] @ W2)  [256 -> 2]
// one wave per row; shuffle reduce
__global__ __launch_bounds__(256) void gemm2_kernel(const float* __restrict__ Z,
                                                    const float* __restrict__ W2,
                                                    const float* __restrict__ dinv,
                                                    float* __restrict__ G2) {
    __shared__ float2 w[HIDDEN];
    int tid = threadIdx.x;
    w[tid] = make_float2(W2[tid * 2], W2[tid * 2 + 1]);
    __syncthreads();
    int wave = tid >> 6, lane = tid & 63;
    int row = blockIdx.x * 4 + wave;
    if (row >= N_NODES) return;
    float4 v = *(const float4*)&Z[(size_t)row * HIDDEN + lane * 4];
    float2 w0 = w[lane * 4 + 0], w1 = w[lane * 4 + 1];
    float2 w2_ = w[lane * 4 + 2], w3 = w[lane * 4 + 3];
    float a0 = v.x * w0.x + v.y * w1.x + v.z * w2_.x + v.w * w3.x;
    float a1 = v.x * w0.y + v.y * w1.y + v.z * w2_.y + v.w * w3.y;
    #pragma unroll
    for (int off = 32; off; off >>= 1) {
        a0 += __shfl_xor(a0, off, 64);
        a1 += __shfl_xor(a1, off, 64);
    }
    if (lane == 0) {
        float dv = dinv[row];
        G2[row * 2 + 0] = dv * a0;
        G2[row * 2 + 1] = dv * a1;
    }
}

// ---------------- agg2: out[d] = dinv[d]*(g2[d] + sum g2[src]) + b2
__global__ __launch_bounds__(256) void agg2_kernel(const float* __restrict__ G2,
                                                   const int* __restrict__ csr,
                                                   const int* __restrict__ rowoff,
                                                   const int* __restrict__ cnt,
                                                   const float* __restrict__ dinv,
                                                   const float* __restrict__ b2,
                                                   float* __restrict__ out) {
    int wave = threadIdx.x >> 6, lane = threadIdx.x & 63;
    int d = blockIdx.x * 4 + wave;
    if (d >= N_NODES) return;
    int beg = rowoff[d], num = cnt[d];
    float a0 = 0.f, a1 = 0.f;
    for (int e = lane; e < num; e += 64) {
        int s = csr[beg + e];
        float2 g = *(const float2*)&G2[s * 2];
        a0 += g.x; a1 += g.y;
    }
    #pragma unroll
    for (int off = 32; off; off >>= 1) {
        a0 += __shfl_xor(a0, off, 64);
        a1 += __shfl_xor(a1, off, 64);
    }
    if (lane == 0) {
        float2 self = *(const float2*)&G2[d * 2];
        float dv = dinv[d];
        out[d * 2 + 0] = dv * (a0 + self.x) + b2[0];
        out[d * 2 + 1] = dv * (a1 + self.y) + b2[1];
    }
}

// ---------------- workspace layout (bytes) ----------------
#define OFF_CNT     0u
#define OFF_ROWOFF  200064u
#define OFF_CURSOR  400128u
#define OFF_DINV    600192u
#define OFF_CSR     800256u
#define OFF_G1      7200256u
#define OFF_Z       58400256u
#define OFF_G2      109600256u
// total ~110.0 MB

extern "C" void kernel_launch(void* const* d_in, const int* in_sizes, int n_in,
                              void* d_out, int out_size, void* d_ws, size_t ws_size,
                              hipStream_t stream) {
    const float* x  = (const float*)d_in[0];
    const float* W1 = (const float*)d_in[1];
    const float* b1 = (const float*)d_in[2];
    const float* W2 = (const float*)d_in[3];
    const float* b2 = (const float*)d_in[4];
    const int*   ei = (const int*)d_in[5];   // int32 per harness contract

    char* ws = (char*)d_ws;
    int*   cnt    = (int*)  (ws + OFF_CNT);
    int*   rowoff = (int*)  (ws + OFF_ROWOFF);
    int*   cursor = (int*)  (ws + OFF_CURSOR);
    float* dinv   = (float*)(ws + OFF_DINV);
    int*   csr    = (int*)  (ws + OFF_CSR);
    float* g1     = (float*)(ws + OFF_G1);
    float* z      = (float*)(ws + OFF_Z);
    float* g2     = (float*)(ws + OFF_G2);
    float* out    = (float*)d_out;

    hipMemsetAsync(cnt, 0, N_NODES * sizeof(int), stream);
    hist_kernel<<<2048, 256, 0, stream>>>(ei, cnt);
    scan_kernel<<<1, 1024, 0, stream>>>(cnt, rowoff, cursor, dinv);
    scatter_kernel<<<2048, 256, 0, stream>>>(ei, cursor, csr);

    dim3 g1grid((N_NODES + 127) / 128, HIDDEN / 128);
    gemm1_kernel<<<g1grid, 256, 0, stream>>>(x, W1, dinv, g1);

    agg1_kernel<<<(N_NODES + 3) / 4, 256, 0, stream>>>(g1, csr, rowoff, cnt, dinv, b1, z);
    gemm2_kernel<<<(N_NODES + 3) / 4, 256, 0, stream>>>(z, W2, dinv, g2);
    agg2_kernel<<<(N_NODES + 3) / 4, 256, 0, stream>>>(g2, csr, rowoff, cnt, dinv, b2, out);
}

// Round 3
// 623.985 us; speedup vs baseline: 1.5269x; 1.5269x over previous
//
#include <hip/hip_runtime.h>
#include <math.h>

#define N_NODES 50000
#define IN_DIM  1000
#define HIDDEN  256
#define N_EDGES 1600000
#define KPAD    1024
#define NBLK    196      // ceil(50000/256)

typedef short bf16x8 __attribute__((ext_vector_type(8)));
typedef float f32x16 __attribute__((ext_vector_type(16)));

__device__ __forceinline__ unsigned short f2bf_rne(float f) {
    unsigned u = __builtin_bit_cast(unsigned, f);
    unsigned r = (u + 0x7FFFu + ((u >> 16) & 1u)) >> 16;
    return (unsigned short)r;
}
__device__ __forceinline__ float bf2f(unsigned short b) {
    unsigned u = ((unsigned)b) << 16;
    return __builtin_bit_cast(float, u);
}

// ---------------- degree histogram ----------------
__global__ void hist_kernel(const int* __restrict__ ei, int* __restrict__ cnt) {
    int e = blockIdx.x * blockDim.x + threadIdx.x;
    int stride = gridDim.x * blockDim.x;
    for (; e < N_EDGES; e += stride) {
        int d = ei[N_EDGES + e];
        if ((unsigned)d < N_NODES) atomicAdd(&cnt[d], 1);
    }
}

// ---------------- 3-phase scan ----------------
__global__ __launch_bounds__(256) void scan_sums(const int* __restrict__ cnt, int* __restrict__ bsum) {
    __shared__ int s[256];
    int t = threadIdx.x;
    int i = blockIdx.x * 256 + t;
    s[t] = (i < N_NODES) ? cnt[i] : 0;
    __syncthreads();
    #pragma unroll
    for (int off = 128; off > 0; off >>= 1) {
        if (t < off) s[t] += s[t + off];
        __syncthreads();
    }
    if (t == 0) bsum[blockIdx.x] = s[0];
}

__global__ __launch_bounds__(256) void scan_top(int* __restrict__ bsum) {
    __shared__ int s[256];
    int t = threadIdx.x;
    int v = (t < NBLK) ? bsum[t] : 0;
    s[t] = v;
    __syncthreads();
    for (int off = 1; off < 256; off <<= 1) {
        int x = (t >= off) ? s[t - off] : 0;
        __syncthreads();
        s[t] += x;
        __syncthreads();
    }
    if (t < NBLK) bsum[t] = s[t] - v;   // exclusive
}

__global__ __launch_bounds__(256) void scan_write(const int* __restrict__ cnt, const int* __restrict__ bsum,
                                                  int* __restrict__ rowoff, int* __restrict__ cursor,
                                                  float* __restrict__ dinv) {
    __shared__ int s[256];
    int t = threadIdx.x;
    int i = blockIdx.x * 256 + t;
    int v = (i < N_NODES) ? cnt[i] : 0;
    s[t] = v;
    __syncthreads();
    for (int off = 1; off < 256; off <<= 1) {
        int x = (t >= off) ? s[t - off] : 0;
        __syncthreads();
        s[t] += x;
        __syncthreads();
    }
    if (i < N_NODES) {
        int ro = bsum[blockIdx.x] + s[t] - v;   // exclusive
        rowoff[i] = ro;
        cursor[i] = ro;
        dinv[i]  = rsqrtf((float)v + 1.0f);
    }
}

// ---------------- counting-sort scatter ----------------
__global__ void scatter_kernel(const int* __restrict__ ei,
                               int* __restrict__ cursor, int* __restrict__ csr) {
    int e = blockIdx.x * blockDim.x + threadIdx.x;
    int stride = gridDim.x * blockDim.x;
    for (; e < N_EDGES; e += stride) {
        int s = ei[e];
        int d = ei[N_EDGES + e];
        if ((unsigned)d < N_NODES && (unsigned)s < N_NODES) {
            int pos = atomicAdd(&cursor[d], 1);
            csr[pos] = s;
        }
    }
}

// ---------------- W1 split+transpose: Wt_h/Wt_l [256 cols][1024 k] bf16 ----------------
__global__ __launch_bounds__(256) void wsplit_kernel(const float* __restrict__ W1,
                                                     unsigned short* __restrict__ Wth,
                                                     unsigned short* __restrict__ Wtl) {
    int idx = blockIdx.x * 256 + threadIdx.x;   // 256*1024 total
    int c = idx >> 10, k = idx & 1023;
    float v = (k < IN_DIM) ? W1[(size_t)k * HIDDEN + c] : 0.0f;
    unsigned short hb = f2bf_rne(v);
    unsigned short lb = f2bf_rne(v - bf2f(hb));
    Wth[idx] = hb;
    Wtl[idx] = lb;
}

// ---------------- GEMM1 (MFMA, 3-product bf16 split, no LDS) ----------------
// G1b[row][col] = bf16( dinv[row] * (X @ W1)[row][col] )
// block = 128 thr = 2 waves (wave w owns cols w*128..w*128+127); block rows = 64
__global__ __launch_bounds__(128) void gemm1_mfma(const float* __restrict__ X,
                                                  const unsigned short* __restrict__ Wth,
                                                  const unsigned short* __restrict__ Wtl,
                                                  const float* __restrict__ dinv,
                                                  unsigned short* __restrict__ G1b) {
    const int tid = threadIdx.x;
    const int w  = tid >> 6;
    const int l  = tid & 63;
    const int lr = l & 31;    // A-row / B-col within frag
    const int lq = l >> 5;    // k half-slot
    const int m0 = blockIdx.x * 64;

    f32x16 acc[2][4] = {};

    for (int step = 0; step < 63; ++step) {       // ceil(1000/16)
        const int kb = step * 16 + lq * 8;
        bf16x8 ah[2], al[2];
        #pragma unroll
        for (int mi = 0; mi < 2; ++mi) {
            int row = m0 + mi * 32 + lr;
            int rc = row < N_NODES ? row : N_NODES - 1;
            bool valid = (row < N_NODES) && (kb < IN_DIM);
            const float* p = X + (size_t)rc * IN_DIM + kb;
            float4 f0 = make_float4(0.f,0.f,0.f,0.f), f1 = f0;
            if (valid) { f0 = *(const float4*)p; f1 = *(const float4*)(p + 4); }
            float f[8] = {f0.x,f0.y,f0.z,f0.w,f1.x,f1.y,f1.z,f1.w};
            #pragma unroll
            for (int j = 0; j < 8; ++j) {
                unsigned short hb = f2bf_rne(f[j]);
                unsigned short lb = f2bf_rne(f[j] - bf2f(hb));
                ah[mi][j] = (short)hb;
                al[mi][j] = (short)lb;
            }
        }
        bf16x8 bh[4], bl[4];
        #pragma unroll
        for (int ni = 0; ni < 4; ++ni) {
            int c = w * 128 + ni * 32 + lr;
            bh[ni] = *(const bf16x8*)(Wth + (size_t)c * KPAD + kb);
            bl[ni] = *(const bf16x8*)(Wtl + (size_t)c * KPAD + kb);
        }
        #pragma unroll
        for (int mi = 0; mi < 2; ++mi)
            #pragma unroll
            for (int ni = 0; ni < 4; ++ni) {
                acc[mi][ni] = __builtin_amdgcn_mfma_f32_32x32x16_bf16(ah[mi], bh[ni], acc[mi][ni], 0, 0, 0);
                acc[mi][ni] = __builtin_amdgcn_mfma_f32_32x32x16_bf16(ah[mi], bl[ni], acc[mi][ni], 0, 0, 0);
                acc[mi][ni] = __builtin_amdgcn_mfma_f32_32x32x16_bf16(al[mi], bh[ni], acc[mi][ni], 0, 0, 0);
            }
    }

    // C/D layout (m74/m101): col = lane&31, row = (reg&3) + 8*(reg>>2) + 4*(lane>>5)
    #pragma unroll
    for (int mi = 0; mi < 2; ++mi)
        #pragma unroll
        for (int r = 0; r < 16; ++r) {
            int row = m0 + mi * 32 + (r & 3) + 8 * (r >> 2) + 4 * lq;
            if (row >= N_NODES) continue;
            float dv = dinv[row];
            #pragma unroll
            for (int ni = 0; ni < 4; ++ni) {
                int col = w * 128 + ni * 32 + lr;
                G1b[(size_t)row * HIDDEN + col] = f2bf_rne(dv * acc[mi][ni][r]);
            }
        }
}

// ---------------- agg1: z = relu(dinv[d]*(g1[d] + sum g1[src]) + b1), g1 in bf16 ----------------
__global__ __launch_bounds__(256) void agg1_kernel(const unsigned short* __restrict__ G,
                                                   const int* __restrict__ csr,
                                                   const int* __restrict__ rowoff,
                                                   const int* __restrict__ cnt,
                                                   const float* __restrict__ dinv,
                                                   const float* __restrict__ b1,
                                                   float* __restrict__ Z) {
    int wave = threadIdx.x >> 6;
    int lane = threadIdx.x & 63;
    int d = blockIdx.x * 4 + wave;
    if (d >= N_NODES) return;
    int c0 = lane * 4;
    ushort4 sv = *(const ushort4*)&G[(size_t)d * HIDDEN + c0];
    float ax = bf2f(sv.x), ay = bf2f(sv.y), az = bf2f(sv.z), aw = bf2f(sv.w);
    int beg = rowoff[d], num = cnt[d];
    for (int e = 0; e < num; ++e) {
        int s = csr[beg + e];
        ushort4 v = *(const ushort4*)&G[(size_t)s * HIDDEN + c0];
        ax += bf2f(v.x); ay += bf2f(v.y); az += bf2f(v.z); aw += bf2f(v.w);
    }
    float dv = dinv[d];
    float4 bb = *(const float4*)&b1[c0];
    float4 o;
    o.x = fmaxf(dv * ax + bb.x, 0.f);
    o.y = fmaxf(dv * ay + bb.y, 0.f);
    o.z = fmaxf(dv * az + bb.z, 0.f);
    o.w = fmaxf(dv * aw + bb.w, 0.f);
    *(float4*)&Z[(size_t)d * HIDDEN + c0] = o;
}

// ---------------- gemm2 + scale ----------------
__global__ __launch_bounds__(256) void gemm2_kernel(const float* __restrict__ Z,
                                                    const float* __restrict__ W2,
                                                    const float* __restrict__ dinv,
                                                    float* __restrict__ G2) {
    __shared__ float2 w[HIDDEN];
    int tid = threadIdx.x;
    w[tid] = make_float2(W2[tid * 2], W2[tid * 2 + 1]);
    __syncthreads();
    int wave = tid >> 6, lane = tid & 63;
    int row = blockIdx.x * 4 + wave;
    if (row >= N_NODES) return;
    float4 v = *(const float4*)&Z[(size_t)row * HIDDEN + lane * 4];
    float2 w0 = w[lane * 4 + 0], w1 = w[lane * 4 + 1];
    float2 w2_ = w[lane * 4 + 2], w3 = w[lane * 4 + 3];
    float a0 = v.x * w0.x + v.y * w1.x + v.z * w2_.x + v.w * w3.x;
    float a1 = v.x * w0.y + v.y * w1.y + v.z * w2_.y + v.w * w3.y;
    #pragma unroll
    for (int off = 32; off; off >>= 1) {
        a0 += __shfl_xor(a0, off, 64);
        a1 += __shfl_xor(a1, off, 64);
    }
    if (lane == 0) {
        float dv = dinv[row];
        G2[row * 2 + 0] = dv * a0;
        G2[row * 2 + 1] = dv * a1;
    }
}

// ---------------- agg2 ----------------
__global__ __launch_bounds__(256) void agg2_kernel(const float* __restrict__ G2,
                                                   const int* __restrict__ csr,
                                                   const int* __restrict__ rowoff,
                                                   const int* __restrict__ cnt,
                                                   const float* __restrict__ dinv,
                                                   const float* __restrict__ b2,
                                                   float* __restrict__ out) {
    int wave = threadIdx.x >> 6, lane = threadIdx.x & 63;
    int d = blockIdx.x * 4 + wave;
    if (d >= N_NODES) return;
    int beg = rowoff[d], num = cnt[d];
    float a0 = 0.f, a1 = 0.f;
    for (int e = lane; e < num; e += 64) {
        int s = csr[beg + e];
        float2 g = *(const float2*)&G2[s * 2];
        a0 += g.x; a1 += g.y;
    }
    #pragma unroll
    for (int off = 32; off; off >>= 1) {
        a0 += __shfl_xor(a0, off, 64);
        a1 += __shfl_xor(a1, off, 64);
    }
    if (lane == 0) {
        float2 self = *(const float2*)&G2[d * 2];
        float dv = dinv[d];
        out[d * 2 + 0] = dv * (a0 + self.x) + b2[0];
        out[d * 2 + 1] = dv * (a1 + self.y) + b2[1];
    }
}

// ---------------- workspace layout (bytes) ----------------
#define OFF_CNT     0u
#define OFF_ROWOFF  262144u
#define OFF_CURSOR  524288u
#define OFF_DINV    786432u
#define OFF_BSUM    1048576u
#define OFF_CSR     1310720u
#define OFF_WTH     8388608u
#define OFF_WTL     8912896u
#define OFF_G1B     9437184u
#define OFF_Z       35651584u
#define OFF_G2      86851584u
// total < 88 MB

extern "C" void kernel_launch(void* const* d_in, const int* in_sizes, int n_in,
                              void* d_out, int out_size, void* d_ws, size_t ws_size,
                              hipStream_t stream) {
    const float* x  = (const float*)d_in[0];
    const float* W1 = (const float*)d_in[1];
    const float* b1 = (const float*)d_in[2];
    const float* W2 = (const float*)d_in[3];
    const float* b2 = (const float*)d_in[4];
    const int*   ei = (const int*)d_in[5];

    char* ws = (char*)d_ws;
    int*   cnt    = (int*)  (ws + OFF_CNT);
    int*   rowoff = (int*)  (ws + OFF_ROWOFF);
    int*   cursor = (int*)  (ws + OFF_CURSOR);
    float* dinv   = (float*)(ws + OFF_DINV);
    int*   bsum   = (int*)  (ws + OFF_BSUM);
    int*   csr    = (int*)  (ws + OFF_CSR);
    unsigned short* wth = (unsigned short*)(ws + OFF_WTH);
    unsigned short* wtl = (unsigned short*)(ws + OFF_WTL);
    unsigned short* g1b = (unsigned short*)(ws + OFF_G1B);
    float* z      = (float*)(ws + OFF_Z);
    float* g2     = (float*)(ws + OFF_G2);
    float* out    = (float*)d_out;

    hipMemsetAsync(cnt, 0, N_NODES * sizeof(int), stream);
    hist_kernel<<<2048, 256, 0, stream>>>(ei, cnt);
    scan_sums<<<NBLK, 256, 0, stream>>>(cnt, bsum);
    scan_top<<<1, 256, 0, stream>>>(bsum);
    scan_write<<<NBLK, 256, 0, stream>>>(cnt, bsum, rowoff, cursor, dinv);
    scatter_kernel<<<2048, 256, 0, stream>>>(ei, cursor, csr);
    wsplit_kernel<<<1024, 256, 0, stream>>>(W1, wth, wtl);

    gemm1_mfma<<<(N_NODES + 63) / 64, 128, 0, stream>>>(x, wth, wtl, dinv, g1b);

    agg1_kernel<<<(N_NODES + 3) / 4, 256, 0, stream>>>(g1b, csr, rowoff, cnt, dinv, b1, z);
    gemm2_kernel<<<(N_NODES + 3) / 4, 256, 0, stream>>>(z, W2, dinv, g2);
    agg2_kernel<<<(N_NODES + 3) / 4, 256, 0, stream>>>(g2, csr, rowoff, cnt, dinv, b2, out);
}